// Round 11
// baseline (152.280 us; speedup 1.0000x reference)
//
#include <hip/hip_runtime.h>

typedef _Float16 h8v __attribute__((ext_vector_type(8)));
typedef float f4v __attribute__((ext_vector_type(4)));

#define RS 136   // halves per LDS row (272 B)
#define SD 68    // dwords per row

__device__ __forceinline__ unsigned pk2f(float a, float b) {
  unsigned short ha = __builtin_bit_cast(unsigned short, (_Float16)a);
  unsigned short hb = __builtin_bit_cast(unsigned short, (_Float16)b);
  return (unsigned)ha | ((unsigned)hb << 16);
}
__device__ __forceinline__ float2 upk(unsigned u) {
  _Float16 lo = __builtin_bit_cast(_Float16, (unsigned short)(u & 0xffffu));
  _Float16 hi = __builtin_bit_cast(_Float16, (unsigned short)(u >> 16));
  return make_float2((float)lo, (float)hi);
}

// Wlf[o*128 + k] = f16(Wl[o][k]), zero-padded to [128][128]
__global__ void prep_kernel(const float* __restrict__ Wl,
                            unsigned short* __restrict__ Wlf) {
  int i = blockIdx.x * 256 + threadIdx.x;
  if (i < 128 * 128) {
    int o = i >> 7, k = i & 127;
    _Float16 v = (_Float16)0.f;
    if (o < 100 && k < 100) v = (_Float16)Wl[o * 100 + k];
    Wlf[i] = __builtin_bit_cast(unsigned short, v);
  }
}

// colpair cp owns col-tiles 2cp, 2cp+1 (tile 7 = zero pad cols).
__device__ __forceinline__ void load_bfrags(
    const unsigned short* __restrict__ Wlf, const float* __restrict__ bl,
    h8v (&B0)[4], h8v (&B1)[4], float& bias0, float& bias1,
    int cp, int quad, int c16) {
  int col0 = cp * 32 + c16;
  int col1 = col0 + 16;
  bias0 = (col0 < 100) ? 2.0f * bl[col0] : 0.f;
  bias1 = (col1 < 100) ? 2.0f * bl[col1] : 0.f;
  const _Float16* w0 = (const _Float16*)Wlf + col0 * 128 + quad * 8;
  const _Float16* w1 = (const _Float16*)Wlf + col1 * 128 + quad * 8;
  B0[0] = *(const h8v*)(w0);      B0[1] = *(const h8v*)(w0 + 32);
  B0[2] = *(const h8v*)(w0 + 64); B0[3] = *(const h8v*)(w0 + 96);
  B1[0] = *(const h8v*)(w1);      B1[1] = *(const h8v*)(w1 + 32);
  B1[2] = *(const h8v*)(w1 + 64); B1[3] = *(const h8v*)(w1 + 96);
}

__device__ __forceinline__ void mfma_8(
    const h8v& A0, const h8v& A1, const h8v& A2, const h8v& A3,
    const h8v (&B0)[4], const h8v (&B1)[4], float bias0, float bias1,
    f4v& a0, f4v& a1) {
  a0 = {bias0, bias0, bias0, bias0};
  a1 = {bias1, bias1, bias1, bias1};
  a0 = __builtin_amdgcn_mfma_f32_16x16x32_f16(A0, B0[0], a0, 0, 0, 0);
  a0 = __builtin_amdgcn_mfma_f32_16x16x32_f16(A1, B0[1], a0, 0, 0, 0);
  a0 = __builtin_amdgcn_mfma_f32_16x16x32_f16(A2, B0[2], a0, 0, 0, 0);
  a0 = __builtin_amdgcn_mfma_f32_16x16x32_f16(A3, B0[3], a0, 0, 0, 0);
  a1 = __builtin_amdgcn_mfma_f32_16x16x32_f16(A0, B1[0], a1, 0, 0, 0);
  a1 = __builtin_amdgcn_mfma_f32_16x16x32_f16(A1, B1[1], a1, 0, 0, 0);
  a1 = __builtin_amdgcn_mfma_f32_16x16x32_f16(A2, B1[2], a1, 0, 0, 0);
  a1 = __builtin_amdgcn_mfma_f32_16x16x32_f16(A3, B1[3], a1, 0, 0, 0);
}

__device__ __forceinline__ void store_cd(
    _Float16* dstE, _Float16* dstO, int rb, const f4v& a0, const f4v& a1,
    int quad, int c16, int col0, int col1) {
  #pragma unroll
  for (int rg = 0; rg < 4; ++rg) {
    int row = rb + quad * 4 + rg;
    _Float16* dr = ((row & 1) ? dstO : dstE) + (size_t)(row >> 1) * RS;
    dr[col0] = (_Float16)fmaxf(a0[rg], 0.f);
    dr[col1] = (_Float16)fmaxf(a1[rg], 0.f);
  }
}

// One level from LDS. pairMode: A = srcE[r]+srcO[r]; else A = srcE[r].
// 8 waves: rowhalf picks alternating row-tiles.
// NOTE: tiles*16 output rows are always written (rows >= nOut are garbage);
// caller must keep dstO >= 8 rows after dstE so garbage never aliases valid.
__device__ __forceinline__ void mfma_level(
    const _Float16* srcE, const _Float16* srcO, bool pairMode,
    _Float16* dstE, _Float16* dstO, int nOut,
    const h8v (&B0)[4], const h8v (&B1)[4], float bias0, float bias1,
    int cp, int rowhalf, int quad, int c16) {
  const int col0 = cp * 32 + c16, col1 = col0 + 16;
  const int tiles = (nOut + 15) >> 4;
  for (int rt = rowhalf; rt < tiles; rt += 2) {
    const int r = rt * 16 + c16;
    const h8v* pe = (const h8v*)(srcE + (size_t)r * RS + quad * 8);
    h8v A0, A1, A2, A3;
    if (pairMode) {
      const h8v* po = (const h8v*)(srcO + (size_t)r * RS + quad * 8);
      A0 = pe[0] + po[0];  A1 = pe[4] + po[4];
      A2 = pe[8] + po[8];  A3 = pe[12] + po[12];
    } else {
      A0 = pe[0]; A1 = pe[4]; A2 = pe[8]; A3 = pe[12];
    }
    f4v a0, a1;
    mfma_8(A0, A1, A2, A3, B0, B1, bias0, bias1, a0, a1);
    store_cd(dstE, dstO, rt * 16, a0, a1, quad, c16, col0, col1);
  }
}

// L9 from global h8 rows (100 halves, 200B stride): A = g[2r] + g[2r+1].
// Reads past row end at k>=100 are multiplied by zero B-columns.
__device__ __forceinline__ void mfma_level_g(
    const _Float16* __restrict__ g, _Float16* dstE, _Float16* dstO,
    const h8v (&B0)[4], const h8v (&B1)[4], float bias0, float bias1,
    int cp, int rowhalf, int quad, int c16) {
  const int col0 = cp * 32 + c16, col1 = col0 + 16;
  for (int rt = rowhalf; rt < 16; rt += 2) {
    const int r = rt * 16 + c16;
    const _Float16* g0 = g + (size_t)(2 * r) * 100 + quad * 8;
    const _Float16* g1 = g0 + 100;
    h8v A0 = *(const h8v*)(g0)      + *(const h8v*)(g1);
    h8v A1 = *(const h8v*)(g0 + 32) + *(const h8v*)(g1 + 32);
    h8v A2 = *(const h8v*)(g0 + 64) + *(const h8v*)(g1 + 64);
    h8v A3 = *(const h8v*)(g0 + 96) + *(const h8v*)(g1 + 96);
    f4v a0, a1;
    mfma_8(A0, A1, A2, A3, B0, B1, bias0, bias1, a0, a1);
    store_cd(dstE, dstO, rt * 16, a0, a1, quad, c16, col0, col1);
  }
}

// Projection of nRows h-rows (E/O split) at level lvl, nodes gbase+tid.
__device__ __forceinline__ void proj_rows(
    const _Float16* E, const _Float16* O, int nRows, const float* WpS,
    float bp0, float bp1, int lvl, long gbase, float* __restrict__ out, int tid) {
  if (tid >= nRows) return;
  const unsigned* row = (const unsigned*)((tid & 1) ? O : E) + (size_t)(tid >> 1) * SD;
  float q0 = bp0, q1 = bp1;
  #pragma unroll
  for (int p = 0; p < 25; ++p) {
    uint2 u = ((const uint2*)row)[p];
    float2 a = upk(u.x), b = upk(u.y);
    q0 = fmaf(a.x, WpS[4*p], fmaf(a.y, WpS[4*p+1],
         fmaf(b.x, WpS[4*p+2], fmaf(b.y, WpS[4*p+3], q0))));
    q1 = fmaf(a.x, WpS[100+4*p], fmaf(a.y, WpS[100+4*p+1],
         fmaf(b.x, WpS[100+4*p+2], fmaf(b.y, WpS[100+4*p+3], q1))));
  }
  long g = gbase + tid;
  long pos = ((g + 1) << (lvl + 1)) - 2 - __popc((unsigned)g);
  out[2 * pos] = q0; out[2 * pos + 1] = q1;
}

// Leaf kernel: 256 leaves/block, 512 threads, levels 0..8; writes 1 h8 row.
__global__ __launch_bounds__(512) void leaf_kernel(
    const int* __restrict__ word_ids, const float* __restrict__ emb,
    const unsigned short* __restrict__ Wlf, const float* __restrict__ bl,
    const float* __restrict__ Wp, const float* __restrict__ bp,
    unsigned* __restrict__ h8g, float* __restrict__ out) {
  __shared__ __align__(16) _Float16 bufA[128 * RS];
  __shared__ __align__(16) _Float16 bufB[128 * RS];
  __shared__ float WpS[200];
  const int tid = threadIdx.x, lane = tid & 63;
  const int wave = __builtin_amdgcn_readfirstlane(tid >> 6);
  const int cp = wave >> 1, rowhalf = wave & 1;
  const int quad = lane >> 4, c16 = lane & 15;
  const int blk = blockIdx.x;

  if (tid < 200) WpS[tid] = Wp[tid];
  {   // zero S1 (=bufA) pad dwords 50..63, 128 rows
    unsigned* Ad = (unsigned*)bufA;
    for (int i = tid; i < 128 * 14; i += 512) Ad[(i / 14) * SD + 50 + (i % 14)] = 0;
  }
  const float bp0 = bp[0], bp1 = bp[1];

  // gather: thread = (leaf l = tid>>1, half hh = tid&1), 13/12 float4 each
  const int l = tid >> 1, hh = tid & 1;
  const long gL = (long)blk * 256 + l;
  const float4* row4 = (const float4*)(emb + (size_t)word_ids[gL] * 100);
  float4 v[13];
  #pragma unroll
  for (int i = 0; i < 13; ++i) {
    int q = 13 * hh + i;
    if (q < 25) v[i] = row4[q];
  }
  __syncthreads();   // WpS + S1-pad ready

  {   // lvl-0 projection (fp32 exact)
    float q0 = 0.f, q1 = 0.f;
    #pragma unroll
    for (int i = 0; i < 13; ++i) {
      int q = 13 * hh + i;
      if (q < 25) {
        q0 = fmaf(v[i].x, WpS[4*q], fmaf(v[i].y, WpS[4*q+1],
             fmaf(v[i].z, WpS[4*q+2], fmaf(v[i].w, WpS[4*q+3], q0))));
        q1 = fmaf(v[i].x, WpS[100+4*q], fmaf(v[i].y, WpS[100+4*q+1],
             fmaf(v[i].z, WpS[100+4*q+2], fmaf(v[i].w, WpS[100+4*q+3], q1))));
      }
    }
    q0 += __shfl_xor(q0, 1, 64);
    q1 += __shfl_xor(q1, 1, 64);
    if (hh == 0) {
      long pos = ((gL + 1) << 1) - 2 - __popc((unsigned)gL);
      out[2 * pos] = q0 + bp0; out[2 * pos + 1] = q1 + bp1;
    }
  }
  {   // pair-sum sibling leaves (threads tid, tid^2) -> S1 rows
    unsigned* Ad = (unsigned*)bufA;
    #pragma unroll
    for (int i = 0; i < 13; ++i) {
      int q = 13 * hh + i;
      if (q < 25) {
        float sx = v[i].x + __shfl_xor(v[i].x, 2, 64);
        float sy = v[i].y + __shfl_xor(v[i].y, 2, 64);
        float sz = v[i].z + __shfl_xor(v[i].z, 2, 64);
        float sw = v[i].w + __shfl_xor(v[i].w, 2, 64);
        if ((tid & 2) == 0) {
          int m = tid >> 2;
          Ad[m * SD + 2*q]     = pk2f(sx, sy);
          Ad[m * SD + 2*q + 1] = pk2f(sz, sw);
        }
      }
    }
  }
  h8v B0[4], B1[4]; float bias0, bias1;
  load_bfrags(Wlf, bl, B0, B1, bias0, bias1, cp, quad, c16);
  __syncthreads();

  // L1: 128 out rows from S1 (pre-summed)
  mfma_level(bufA, nullptr, false, bufB, bufB + 64 * RS, 128,
             B0, B1, bias0, bias1, cp, rowhalf, quad, c16);
  __syncthreads();

  const _Float16 *sE = bufB, *sO = bufB + 64 * RS;
  int n = 64;                       // nOut for L2
  #pragma unroll 1
  for (int j = 0; j < 7; ++j) {     // levels 2..8
    _Float16* d = (j & 1) ? bufB : bufA;
    int oOff = (n >> 1) > 8 ? (n >> 1) : 8;   // E spans >=8 rows: garbage 16-row
                                              // footprint never aliases valid O
    mfma_level(sE, sO, true, d, d + (size_t)oOff * RS, n,
               B0, B1, bias0, bias1, cp, rowhalf, quad, c16);
    proj_rows(sE, sO, n * 2, WpS, bp0, bp1, j + 1, (long)blk * (n * 2), out, tid);
    __syncthreads();
    sE = d; sO = d + (size_t)oOff * RS;
    n >>= 1;
  }
  // L8 row (proj of it happens in tail kernel)
  if (tid < 50) h8g[(size_t)blk * 50 + tid] = ((const unsigned*)sE)[tid];
}

// Tail kernel: 1 block, 512 threads, levels 9..17 from 512 global h8 rows.
__global__ __launch_bounds__(512) void tail_kernel(
    const _Float16* __restrict__ h8g, const unsigned short* __restrict__ Wlf,
    const float* __restrict__ bl, const float* __restrict__ Wp,
    const float* __restrict__ bp, float* __restrict__ out) {
  __shared__ __align__(16) _Float16 bufA[256 * RS];   // 69632 B
  __shared__ __align__(16) _Float16 bufB[128 * RS];   // 34816 B
  __shared__ float WpS[200];
  const int tid = threadIdx.x, lane = tid & 63;
  const int wave = __builtin_amdgcn_readfirstlane(tid >> 6);
  const int cp = wave >> 1, rowhalf = wave & 1;
  const int quad = lane >> 4, c16 = lane & 15;

  if (tid < 200) WpS[tid] = Wp[tid];
  h8v B0[4], B1[4]; float bias0, bias1;
  load_bfrags(Wlf, bl, B0, B1, bias0, bias1, cp, quad, c16);
  __syncthreads();
  const float bp0 = bp[0], bp1 = bp[1];

  {   // L8 projection straight from global (512 rows)
    const unsigned* row = (const unsigned*)h8g + (size_t)tid * 50;
    float q0 = bp0, q1 = bp1;
    #pragma unroll
    for (int p = 0; p < 25; ++p) {
      uint2 u = ((const uint2*)row)[p];
      float2 a = upk(u.x), b = upk(u.y);
      q0 = fmaf(a.x, WpS[4*p], fmaf(a.y, WpS[4*p+1],
           fmaf(b.x, WpS[4*p+2], fmaf(b.y, WpS[4*p+3], q0))));
      q1 = fmaf(a.x, WpS[100+4*p], fmaf(a.y, WpS[100+4*p+1],
           fmaf(b.x, WpS[100+4*p+2], fmaf(b.y, WpS[100+4*p+3], q1))));
    }
    long g = tid;
    long pos = ((g + 1) << 9) - 2 - __popc((unsigned)g);
    out[2 * pos] = q0; out[2 * pos + 1] = q1;
  }

  // L9: 256 out rows, A-operands summed from global
  mfma_level_g(h8g, bufA, bufA + 128 * RS, B0, B1, bias0, bias1,
               cp, rowhalf, quad, c16);
  __syncthreads();

  const _Float16 *sE = bufA, *sO = bufA + 128 * RS;
  int n = 128;                      // nOut for L10
  #pragma unroll 1
  for (int j = 0; j < 8; ++j) {     // levels 10..17
    _Float16* d = (j & 1) ? bufA : bufB;
    int oOff = (n >> 1) > 8 ? (n >> 1) : 8;   // same anti-alias guarantee
    mfma_level(sE, sO, true, d, d + (size_t)oOff * RS, n,
               B0, B1, bias0, bias1, cp, rowhalf, quad, c16);
    proj_rows(sE, sO, n * 2, WpS, bp0, bp1, 9 + j, 0, out, tid);
    __syncthreads();
    sE = d; sO = d + (size_t)oOff * RS;
    n >>= 1;
  }
  // root (level 17)
  proj_rows(sE, sO, 1, WpS, bp0, bp1, 17, 0, out, tid);
}

extern "C" void kernel_launch(void* const* d_in, const int* in_sizes, int n_in,
                              void* d_out, int out_size, void* d_ws, size_t ws_size,
                              hipStream_t stream) {
  const int*   word_ids = (const int*)  d_in[0];
  const float* emb      = (const float*)d_in[1];
  const float* Wl       = (const float*)d_in[2];
  const float* bl       = (const float*)d_in[3];
  const float* Wp       = (const float*)d_in[4];
  const float* bp       = (const float*)d_in[5];
  float* out = (float*)d_out;

  unsigned short* Wlf = (unsigned short*)d_ws;                 // 32 KB
  unsigned* h8g = (unsigned*)((char*)d_ws + 32768);            // 512*50 dwords

  prep_kernel<<<64, 256, 0, stream>>>(Wl, Wlf);
  // levels 0..8: 512 blocks x 256 leaves -> h8g (512 rows)
  leaf_kernel<<<512, 512, 0, stream>>>(word_ids, emb, Wlf, bl, Wp, bp, h8g, out);
  // levels 9..17 (+ proj l8): one block
  tail_kernel<<<1, 512, 0, stream>>>((const _Float16*)h8g, Wlf, bl, Wp, bp, out);
}